// Round 5
// baseline (579.214 us; speedup 1.0000x reference)
//
#include <hip/hip_runtime.h>

// SelectionGNN clique+line. I/O: float32 (per reference). Internals: bf16 MFMA
// with fp32 accumulate; intermediates f32 (MFMA inputs rounded once, same as
// rounding-at-staging). B=8, N=4096, E=1, K=3, F=[16,32,16], MLP 65536->64->1.
// R5: global_load_lds(16B) staging of bf16 A/B with XOR-swizzled unpadded LDS,
// 128x64 tiles -> 1024 blocks (4/CU, 16 waves/CU), XCD-swizzled N-tiles.

#define NN 4096
#define BB 8

typedef unsigned short u16;
typedef unsigned int   u32;

typedef __attribute__((ext_vector_type(8))) short bf16x8;  // 8 bf16 = 4 VGPRs
typedef __attribute__((ext_vector_type(4))) float f32x4;

__device__ __forceinline__ u16 f2bf(float f) {
    union { float f; u32 i; } c; c.f = f;
    u32 i = c.i;
    u32 r = (i + 0x7FFFu + ((i >> 16) & 1u)) >> 16;  // RTNE
    return (u16)r;
}

__device__ __forceinline__ void gload_lds16(const u16* g, u16* l) {
    __builtin_amdgcn_global_load_lds(
        (__attribute__((address_space(1))) void*)g,
        (__attribute__((address_space(3))) void*)l, 16, 0, 0);
}

// ---------------------------------------------------------------------------
// f32 -> bf16 conversion, grid-stride, float4 -> ushort4. n % 4 == 0.
// ---------------------------------------------------------------------------
__global__ __launch_bounds__(256) void cvt_f32_bf16(const float* __restrict__ in,
                                                    u16* __restrict__ out, int n)
{
    int i = (blockIdx.x * 256 + threadIdx.x) * 4;
    const int stride = gridDim.x * 256 * 4;
    for (; i < n; i += stride) {
        float4 v = *(const float4*)(in + i);
        ushort4 o;
        o.x = f2bf(v.x); o.y = f2bf(v.y); o.z = f2bf(v.z); o.w = f2bf(v.w);
        *(ushort4*)(out + i) = o;
    }
}

// ---------------------------------------------------------------------------
// Split-K diffusion, 128(M) x 64(N) tile, BK=64:
//   Out[r,n] += sum_{k in slice} Z[r,k] * S[n,k]   (C = Z*S^T, f32 atomics)
// TA: u16 (bf16 A, async global_load_lds) or float (VGPR-convert staging).
// TB: u16 (pre-converted S, async) or float (fallback).
// LDS: unpadded, XOR-swizzled granules: slot(r,g) = g ^ (r&7); 16B granules.
// grid: (64, M/128, KS). blockIdx.x XCD-swizzled (8 consecutive ntiles/XCD).
// 256 threads = 4 waves stacked in M; wave owns 32(M)x64(N) = 2x4 mfma accs.
// ---------------------------------------------------------------------------
template <typename TA, typename TB>
__global__ __launch_bounds__(256) void diffuse(const TA* __restrict__ Z,
                                               const TB* __restrict__ S,
                                               float* __restrict__ Out)
{
    __shared__ u16 As[128 * 64];   // 16 KB, swizzled
    __shared__ u16 Bs[64 * 64];    //  8 KB, swizzled

    const int bx    = blockIdx.x;                   // 0..63
    const int ntile = ((bx & 7) << 3) | (bx >> 3);  // 8 contiguous ntiles/XCD
    const int nBase = ntile * 64;
    const int mBase = blockIdx.y * 128;
    const int tid   = threadIdx.x;
    const int lane  = tid & 63;
    const int wv    = tid >> 6;
    const int quad  = lane >> 4;
    const int l16   = lane & 15;

    const int kSlice = NN / (int)gridDim.z;
    const int kStart = (int)blockIdx.z * kSlice;

    // async staging decomposition: wave-issue = 64 lanes x 16 B = 8 rows
    const int rl   = lane >> 3;        // row within 8-row group
    const int gsl  = lane & 7;         // dest granule slot
    const int gsrc = gsl ^ rl;         // source granule (XOR swizzle)

    // f32 staging decomposition: 256 thr x float4 = 16 rows x 64 cols / pass
    const int fr = tid >> 4;           // 0..15
    const int fc = (tid & 15) * 4;     // 0,4,..,60

    f32x4 acc[2][4];
#pragma unroll
    for (int i = 0; i < 2; ++i)
#pragma unroll
        for (int j = 0; j < 4; ++j) acc[i][j] = (f32x4){0.f, 0.f, 0.f, 0.f};

    for (int k0 = kStart; k0 < kStart + kSlice; k0 += 64) {
        // ---- A tile: 128 x 64 ----
        if constexpr (sizeof(TA) == 2) {
#pragma unroll
            for (int j = 0; j < 4; ++j) {
                const int rb = (wv * 4 + j) * 8;   // 0..120
                gload_lds16((const u16*)Z + (size_t)(mBase + rb + rl) * NN + k0 + gsrc * 8,
                            &As[rb * 64]);
            }
        } else {
#pragma unroll
            for (int p = 0; p < 8; ++p) {
                const int r = fr + p * 16;
                float4 v = *(const float4*)((const float*)Z + (size_t)(mBase + r) * NN + k0 + fc);
                ushort4 o;
                o.x = f2bf(v.x); o.y = f2bf(v.y); o.z = f2bf(v.z); o.w = f2bf(v.w);
                const int dc = (((fc >> 3) ^ (r & 7)) << 3) | (fc & 7);
                *(ushort4*)&As[r * 64 + dc] = o;
            }
        }
        // ---- B tile: 64 x 64 ----
        if constexpr (sizeof(TB) == 2) {
#pragma unroll
            for (int j = 0; j < 2; ++j) {
                const int rb = (wv * 2 + j) * 8;   // 0..56
                gload_lds16((const u16*)S + (size_t)(nBase + rb + rl) * NN + k0 + gsrc * 8,
                            &Bs[rb * 64]);
            }
        } else {
#pragma unroll
            for (int p = 0; p < 4; ++p) {
                const int r = fr + p * 16;
                float4 v = *(const float4*)((const float*)S + (size_t)(nBase + r) * NN + k0 + fc);
                ushort4 o;
                o.x = f2bf(v.x); o.y = f2bf(v.y); o.z = f2bf(v.z); o.w = f2bf(v.w);
                const int dc = (((fc >> 3) ^ (r & 7)) << 3) | (fc & 7);
                *(ushort4*)&Bs[r * 64 + dc] = o;
            }
        }
        __syncthreads();

#pragma unroll
        for (int s = 0; s < 2; ++s) {
            const int g = s * 4 + quad;            // k-granule 0..7
            bf16x8 af[2], bf[4];
#pragma unroll
            for (int mi = 0; mi < 2; ++mi) {
                const int r = wv * 32 + mi * 16 + l16;
                af[mi] = *(const bf16x8*)&As[r * 64 + ((g ^ (r & 7)) << 3)];
            }
#pragma unroll
            for (int ni = 0; ni < 4; ++ni) {
                const int r = ni * 16 + l16;
                bf[ni] = *(const bf16x8*)&Bs[r * 64 + ((g ^ (r & 7)) << 3)];
            }
#pragma unroll
            for (int mi = 0; mi < 2; ++mi)
#pragma unroll
                for (int ni = 0; ni < 4; ++ni)
                    acc[mi][ni] = __builtin_amdgcn_mfma_f32_16x16x32_bf16(
                        af[mi], bf[ni], acc[mi][ni], 0, 0, 0);
        }
        __syncthreads();
    }

    // D mapping: col = lane&15, row = quad*4 + reg.  Atomic accumulate.
#pragma unroll
    for (int mi = 0; mi < 2; ++mi)
#pragma unroll
        for (int ni = 0; ni < 4; ++ni) {
            const int row0 = mBase + wv * 32 + mi * 16 + quad * 4;
            const int col  = nBase + ni * 16 + l16;
#pragma unroll
            for (int i = 0; i < 4; ++i)
                atomicAdd(&Out[(size_t)(row0 + i) * NN + col], acc[mi][ni][i]);
        }
}

// ---------------------------------------------------------------------------
// Tap combine + ReLU (f32 in/out, plus bf16 shadow copy for next diffuse A):
// out[b,g,n] = relu( bias[g] + sum_{k<3} sum_{f<FIN} W[g,k,f] * z_k[b,f,n] )
// ---------------------------------------------------------------------------
template <int FIN, int FOUT>
__global__ __launch_bounds__(256) void combine_relu(
    const float* __restrict__ z0, const float* __restrict__ z1,
    const float* __restrict__ z2, const float* __restrict__ W,
    const float* __restrict__ bias, float* __restrict__ out,
    u16* __restrict__ outb)
{
    __shared__ float hs[FOUT * 3 * FIN];
    __shared__ float bs[FOUT];
    for (int i = threadIdx.x; i < FOUT * 3 * FIN; i += 256) hs[i] = W[i];
    if (threadIdx.x < FOUT) bs[threadIdx.x] = bias[threadIdx.x];
    __syncthreads();

    const int nb = NN / 256;                 // 16
    const int b  = blockIdx.x / nb;
    const int n  = (blockIdx.x % nb) * 256 + threadIdx.x;

    float zv[3][FIN];
    const float* zp0 = z0 + (size_t)b * FIN * NN + n;
    const float* zp1 = z1 + (size_t)b * FIN * NN + n;
    const float* zp2 = z2 + (size_t)b * FIN * NN + n;
#pragma unroll
    for (int f = 0; f < FIN; ++f) {
        zv[0][f] = zp0[(size_t)f * NN];
        zv[1][f] = zp1[(size_t)f * NN];
        zv[2][f] = zp2[(size_t)f * NN];
    }

    float* op = out  + (size_t)b * FOUT * NN + n;
    u16*   ob = outb + (size_t)b * FOUT * NN + n;
    for (int g = 0; g < FOUT; ++g) {
        float acc = bs[g];
#pragma unroll
        for (int k = 0; k < 3; ++k)
#pragma unroll
            for (int f = 0; f < FIN; ++f)
                acc = fmaf(hs[(g * 3 + k) * FIN + f], zv[k][f], acc);
        const float r = fmaxf(acc, 0.f);
        op[(size_t)g * NN] = r;
        ob[(size_t)g * NN] = f2bf(r);
    }
}

// ---------------------------------------------------------------------------
// MLP layer 1, split-K: h1raw[b,j] += sum_{slice} y[b,i]*Wm1[j,i].
// grid: (64, 8); h1raw pre-zeroed; bias+ReLU folded into mlp2.
// ---------------------------------------------------------------------------
__global__ __launch_bounds__(256) void mlp1(const float* __restrict__ y,
                                            const float* __restrict__ Wm1,
                                            float* __restrict__ h1raw)
{
    const int j    = blockIdx.x;
    const int base = blockIdx.y * 8192;
    const int D    = 16 * NN;  // 65536

    float acc[BB];
#pragma unroll
    for (int b = 0; b < BB; ++b) acc[b] = 0.f;

    const float* wrow = Wm1 + (size_t)j * D + base;
    for (int idx = threadIdx.x * 4; idx < 8192; idx += 256 * 4) {
        float4 w = *(const float4*)(wrow + idx);
#pragma unroll
        for (int b = 0; b < BB; ++b) {
            float4 yv = *(const float4*)(y + (size_t)b * D + base + idx);
            acc[b] = fmaf(w.x, yv.x, acc[b]);
            acc[b] = fmaf(w.y, yv.y, acc[b]);
            acc[b] = fmaf(w.z, yv.z, acc[b]);
            acc[b] = fmaf(w.w, yv.w, acc[b]);
        }
    }

    __shared__ float red[BB][4];
    const int lane = threadIdx.x & 63;
    const int w    = threadIdx.x >> 6;
#pragma unroll
    for (int b = 0; b < BB; ++b) {
        float v = acc[b];
        for (int off = 32; off > 0; off >>= 1) v += __shfl_down(v, off, 64);
        if (lane == 0) red[b][w] = v;
    }
    __syncthreads();
    if (threadIdx.x < BB) {
        const int b = threadIdx.x;
        atomicAdd(&h1raw[b * 64 + j],
                  red[b][0] + red[b][1] + red[b][2] + red[b][3]);
    }
}

// ---------------------------------------------------------------------------
// MLP layer 2 (+ layer-1 bias/ReLU). 1 block, 64 lanes.
// ---------------------------------------------------------------------------
__global__ void mlp2(const float* __restrict__ h1raw,
                     const float* __restrict__ bm1,
                     const float* __restrict__ Wm2,
                     const float* __restrict__ bm2, float* __restrict__ out)
{
    const int lane = threadIdx.x;  // 0..63
    const float w    = Wm2[lane];
    const float b1   = bm1[lane];
    const float bias = bm2[0];
    for (int b = 0; b < BB; ++b) {
        float v = fmaxf(h1raw[b * 64 + lane] + b1, 0.f) * w;
        for (int off = 32; off > 0; off >>= 1) v += __shfl_down(v, off, 64);
        if (lane == 0) out[b] = v + bias;
    }
}

// ---------------------------------------------------------------------------
extern "C" void kernel_launch(void* const* d_in, const int* in_sizes, int n_in,
                              void* d_out, int out_size, void* d_ws, size_t ws_size,
                              hipStream_t stream)
{
    const float* x   = (const float*)d_in[0];   // [8,16,4096]
    const float* Sc  = (const float*)d_in[1];   // [1,4096,4096]
    const float* Sl  = (const float*)d_in[2];   // [1,4096,4096]
    const float* Wc1 = (const float*)d_in[3];
    const float* bc1 = (const float*)d_in[4];
    const float* Wc2 = (const float*)d_in[5];
    const float* bc2 = (const float*)d_in[6];
    const float* Wl1 = (const float*)d_in[7];
    const float* bl1 = (const float*)d_in[8];
    const float* Wl2 = (const float*)d_in[9];
    const float* bl2 = (const float*)d_in[10];
    const float* Wm1 = (const float*)d_in[11];  // [64,65536]
    const float* bm1 = (const float*)d_in[12];
    const float* Wm2 = (const float*)d_in[13];  // [1,64]
    const float* bm2 = (const float*)d_in[14];
    float* out = (float*)d_out;                 // [8,1] f32

    char* ws = (char*)d_ws;
    float* z1   = (float*)(ws);                  // 4 MB ([8,32,4096] f32 max)
    float* z2   = (float*)(ws + (4u << 20));     // 4 MB
    float* yA   = (float*)(ws + (8u << 20));     // 4 MB (32-feat layers)
    float* yB   = (float*)(ws + (12u << 20));    // 2 MB (16-feat layers)
    u16*   bufP = (u16*)(ws + (14u << 20));      // 2 MB bf16 shadow (A operand)
    float* h1   = (float*)(ws + (16u << 20));    // 2 KB
    u16*   Scb  = (u16*)(ws + (17u << 20));      // 32 MB
    u16*   Slb  = Scb + (size_t)NN * NN;         // 32 MB
    const size_t needed = (17u << 20) + 2 * (size_t)NN * NN * sizeof(u16);
    const bool bigws = ws_size >= needed;

    const dim3 blk(256);
    const dim3 gridCmb(BB * NN / 256);           // 128
    const dim3 g2(64, 1, 16);                    // M=128: 1024 blocks, slice 256
    const dim3 g4(64, 2, 8);                     // M=256: 1024 blocks, slice 512

    const size_t sz128 = (size_t)128 * NN * sizeof(float);  // 2 MB
    const size_t sz256 = (size_t)256 * NN * sizeof(float);  // 4 MB

#define ZERO(p, b) hipMemsetAsync((p), 0, (b), stream)

    if (bigws) {
        cvt_f32_bf16<<<1024, blk, 0, stream>>>(Sc, Scb, NN * NN);
        cvt_f32_bf16<<<1024, blk, 0, stream>>>(Sl, Slb, NN * NN);
        cvt_f32_bf16<<<256, blk, 0, stream>>>(x, bufP, 128 * NN);
        // Layer 1: clique, Fin=16 (M=128) -> Fout=32
        ZERO(z1, sz128); diffuse<u16,  u16><<<g2, blk, 0, stream>>>(bufP, Scb, z1);
        ZERO(z2, sz128); diffuse<float,u16><<<g2, blk, 0, stream>>>(z1,   Scb, z2);
        combine_relu<16, 32><<<gridCmb, blk, 0, stream>>>(x, z1, z2, Wc1, bc1, yA, bufP);
        // Layer 2: clique, Fin=32 (M=256) -> Fout=16
        ZERO(z1, sz256); diffuse<u16,  u16><<<g4, blk, 0, stream>>>(bufP, Scb, z1);
        ZERO(z2, sz256); diffuse<float,u16><<<g4, blk, 0, stream>>>(z1,   Scb, z2);
        combine_relu<32, 16><<<gridCmb, blk, 0, stream>>>(yA, z1, z2, Wc2, bc2, yB, bufP);
        // Layer 3: line, Fin=16 (M=128) -> Fout=32
        ZERO(z1, sz128); diffuse<u16,  u16><<<g2, blk, 0, stream>>>(bufP, Slb, z1);
        ZERO(z2, sz128); diffuse<float,u16><<<g2, blk, 0, stream>>>(z1,   Slb, z2);
        combine_relu<16, 32><<<gridCmb, blk, 0, stream>>>(yB, z1, z2, Wl1, bl1, yA, bufP);
        // Layer 4: line, Fin=32 (M=256) -> Fout=16
        ZERO(z1, sz256); diffuse<u16,  u16><<<g4, blk, 0, stream>>>(bufP, Slb, z1);
        ZERO(z2, sz256); diffuse<float,u16><<<g4, blk, 0, stream>>>(z1,   Slb, z2);
        combine_relu<32, 16><<<gridCmb, blk, 0, stream>>>(yA, z1, z2, Wl2, bl2, yB, bufP);
    } else {
        // Fallback: f32 S + f32 A, converted during staging.
        ZERO(z1, sz128); diffuse<float,float><<<g2, blk, 0, stream>>>(x,  Sc, z1);
        ZERO(z2, sz128); diffuse<float,float><<<g2, blk, 0, stream>>>(z1, Sc, z2);
        combine_relu<16, 32><<<gridCmb, blk, 0, stream>>>(x, z1, z2, Wc1, bc1, yA, bufP);
        ZERO(z1, sz256); diffuse<float,float><<<g4, blk, 0, stream>>>(yA, Sc, z1);
        ZERO(z2, sz256); diffuse<float,float><<<g4, blk, 0, stream>>>(z1, Sc, z2);
        combine_relu<32, 16><<<gridCmb, blk, 0, stream>>>(yA, z1, z2, Wc2, bc2, yB, bufP);
        ZERO(z1, sz128); diffuse<float,float><<<g2, blk, 0, stream>>>(yB, Sl, z1);
        ZERO(z2, sz128); diffuse<float,float><<<g2, blk, 0, stream>>>(z1, Sl, z2);
        combine_relu<16, 32><<<gridCmb, blk, 0, stream>>>(yB, z1, z2, Wl1, bl1, yA, bufP);
        ZERO(z1, sz256); diffuse<float,float><<<g4, blk, 0, stream>>>(yA, Sl, z1);
        ZERO(z2, sz256); diffuse<float,float><<<g4, blk, 0, stream>>>(z1, Sl, z2);
        combine_relu<32, 16><<<gridCmb, blk, 0, stream>>>(yA, z1, z2, Wl2, bl2, yB, bufP);
    }
    ZERO(h1, 64 * BB * sizeof(float));
    mlp1<<<dim3(64, 8), blk, 0, stream>>>(yB, Wm1, h1);
    mlp2<<<1, 64, 0, stream>>>(h1, bm1, Wm2, bm2, out);
#undef ZERO
}

// Round 6
// 399.264 us; speedup vs baseline: 1.4507x; 1.4507x over previous
//
#include <hip/hip_runtime.h>

// SelectionGNN clique+line. I/O: float32. Internals: bf16 end-to-end with f32
// accumulation (MFMA + reduce). B=8, N=4096, E=1, K=3, F=[16,32,16],
// MLP 65536->64->1.
// R6: split-K diffuse writes bf16 PARTIAL PLANES (plain stores, no atomics);
// reduce_part sums them. All intermediates bf16. No per-diffuse memsets.

#define NN 4096
#define BB 8

typedef unsigned short u16;
typedef unsigned int   u32;

typedef __attribute__((ext_vector_type(8))) short bf16x8;  // 8 bf16 = 4 VGPRs
typedef __attribute__((ext_vector_type(4))) float f32x4;

__device__ __forceinline__ u16 f2bf(float f) {
    union { float f; u32 i; } c; c.f = f;
    u32 i = c.i;
    u32 r = (i + 0x7FFFu + ((i >> 16) & 1u)) >> 16;  // RTNE
    return (u16)r;
}
__device__ __forceinline__ float bf2f(u16 u) {
    union { u32 i; float f; } c; c.i = ((u32)u) << 16; return c.f;
}

__device__ __forceinline__ void gload_lds16(const u16* g, u16* l) {
    __builtin_amdgcn_global_load_lds(
        (__attribute__((address_space(1))) void*)g,
        (__attribute__((address_space(3))) void*)l, 16, 0, 0);
}

// ---------------------------------------------------------------------------
// f32 -> bf16 conversion, grid-stride, float4 -> ushort4. n % 4 == 0.
// ---------------------------------------------------------------------------
__global__ __launch_bounds__(256) void cvt_f32_bf16(const float* __restrict__ in,
                                                    u16* __restrict__ out, int n)
{
    int i = (blockIdx.x * 256 + threadIdx.x) * 4;
    const int stride = gridDim.x * 256 * 4;
    for (; i < n; i += stride) {
        float4 v = *(const float4*)(in + i);
        ushort4 o;
        o.x = f2bf(v.x); o.y = f2bf(v.y); o.z = f2bf(v.z); o.w = f2bf(v.w);
        *(ushort4*)(out + i) = o;
    }
}

// ---------------------------------------------------------------------------
// Split-K diffusion, 128(M) x 64(N) tile, BK=64, bf16 A/B via async LDS:
//   Part[kz][r,n] = sum_{k in slice} Z[r,k] * S[n,k]   (bf16 partial planes)
// LDS unpadded, XOR-swizzled 16B granules: slot(r,g) = g ^ (r&7).
// grid: (64, M/128, KS). blockIdx.x XCD-swizzled (8 contiguous ntiles/XCD,
// 512-row S slice = 4 MB = one XCD L2). 4 waves stacked in M; wave owns
// 32x64 via 2x4 mfma_f32_16x16x32_bf16.
// ---------------------------------------------------------------------------
__global__ __launch_bounds__(256) void diffuse(const u16* __restrict__ Z,
                                               const u16* __restrict__ S,
                                               u16* __restrict__ Part)
{
    __shared__ u16 As[128 * 64];   // 16 KB, swizzled
    __shared__ u16 Bs[64 * 64];    //  8 KB, swizzled

    const int bx    = blockIdx.x;                   // 0..63
    const int ntile = ((bx & 7) << 3) | (bx >> 3);  // XCD swizzle
    const int nBase = ntile * 64;
    const int mBase = blockIdx.y * 128;
    const int tid   = threadIdx.x;
    const int lane  = tid & 63;
    const int wv    = tid >> 6;
    const int quad  = lane >> 4;
    const int l16   = lane & 15;

    const int kSlice = NN / (int)gridDim.z;
    const int kStart = (int)blockIdx.z * kSlice;

    // async staging: wave-issue = 64 lanes x 16 B = 8 rows x 8 granules
    const int rl   = lane >> 3;        // row within 8-row group
    const int gsl  = lane & 7;         // dest granule slot
    const int gsrc = gsl ^ rl;         // source granule (XOR swizzle)

    f32x4 acc[2][4];
#pragma unroll
    for (int i = 0; i < 2; ++i)
#pragma unroll
        for (int j = 0; j < 4; ++j) acc[i][j] = (f32x4){0.f, 0.f, 0.f, 0.f};

    for (int k0 = kStart; k0 < kStart + kSlice; k0 += 64) {
        // A tile: 128 x 64
#pragma unroll
        for (int j = 0; j < 4; ++j) {
            const int rb = (wv * 4 + j) * 8;   // 0..120
            gload_lds16(Z + (size_t)(mBase + rb + rl) * NN + k0 + gsrc * 8,
                        &As[rb * 64]);
        }
        // B tile: 64 x 64
#pragma unroll
        for (int j = 0; j < 2; ++j) {
            const int rb = (wv * 2 + j) * 8;   // 0..56
            gload_lds16(S + (size_t)(nBase + rb + rl) * NN + k0 + gsrc * 8,
                        &Bs[rb * 64]);
        }
        __syncthreads();

#pragma unroll
        for (int s = 0; s < 2; ++s) {
            const int g = s * 4 + quad;        // k-granule 0..7
            bf16x8 af[2], bf[4];
#pragma unroll
            for (int mi = 0; mi < 2; ++mi) {
                const int r = wv * 32 + mi * 16 + l16;
                af[mi] = *(const bf16x8*)&As[r * 64 + ((g ^ (r & 7)) << 3)];
            }
#pragma unroll
            for (int ni = 0; ni < 4; ++ni) {
                const int r = ni * 16 + l16;
                bf[ni] = *(const bf16x8*)&Bs[r * 64 + ((g ^ (r & 7)) << 3)];
            }
#pragma unroll
            for (int mi = 0; mi < 2; ++mi)
#pragma unroll
                for (int ni = 0; ni < 4; ++ni)
                    acc[mi][ni] = __builtin_amdgcn_mfma_f32_16x16x32_bf16(
                        af[mi], bf[ni], acc[mi][ni], 0, 0, 0);
        }
        __syncthreads();
    }

    // D mapping: col = lane&15, row = quad*4 + reg.  Plain bf16 stores into
    // this block's k-slice plane.
    const size_t plane = (size_t)gridDim.y * 128 * NN;
    u16* pp = Part + (size_t)blockIdx.z * plane;
#pragma unroll
    for (int mi = 0; mi < 2; ++mi)
#pragma unroll
        for (int ni = 0; ni < 4; ++ni) {
            const int row0 = mBase + wv * 32 + mi * 16 + quad * 4;
            const int col  = nBase + ni * 16 + l16;
#pragma unroll
            for (int i = 0; i < 4; ++i)
                pp[(size_t)(row0 + i) * NN + col] = f2bf(acc[mi][ni][i]);
        }
}

// ---------------------------------------------------------------------------
// Sum KS bf16 partial planes (f32 accumulate) -> bf16 z.
// Vectorized 8 bf16 (uint4) per thread-iter.
// ---------------------------------------------------------------------------
template <int KS>
__global__ __launch_bounds__(256) void reduce_part(const u16* __restrict__ part,
                                                   int planeElems,
                                                   u16* __restrict__ outb)
{
    const int base   = (blockIdx.x * 256 + threadIdx.x) * 8;
    const int stride = gridDim.x * 256 * 8;
    for (int i = base; i < planeElems; i += stride) {
        float s[8];
#pragma unroll
        for (int e = 0; e < 8; ++e) s[e] = 0.f;
#pragma unroll
        for (int p = 0; p < KS; ++p) {
            uint4 v = *(const uint4*)(part + (size_t)p * planeElems + i);
            const u32 w[4] = {v.x, v.y, v.z, v.w};
#pragma unroll
            for (int q = 0; q < 4; ++q) {
                union { u32 i; float f; } lo, hi;
                lo.i = w[q] << 16;
                hi.i = w[q] & 0xFFFF0000u;
                s[q * 2]     += lo.f;
                s[q * 2 + 1] += hi.f;
            }
        }
        uint4 o;
        o.x = (u32)f2bf(s[0]) | ((u32)f2bf(s[1]) << 16);
        o.y = (u32)f2bf(s[2]) | ((u32)f2bf(s[3]) << 16);
        o.z = (u32)f2bf(s[4]) | ((u32)f2bf(s[5]) << 16);
        o.w = (u32)f2bf(s[6]) | ((u32)f2bf(s[7]) << 16);
        *(uint4*)(outb + i) = o;
    }
}

// ---------------------------------------------------------------------------
// Tap combine + ReLU, bf16 in/out (f32 math):
// out[b,g,n] = relu( bias[g] + sum_{k<3} sum_{f<FIN} W[g,k,f] * z_k[b,f,n] )
// ---------------------------------------------------------------------------
template <int FIN, int FOUT>
__global__ __launch_bounds__(256) void combine_relu(
    const u16* __restrict__ z0, const u16* __restrict__ z1,
    const u16* __restrict__ z2, const float* __restrict__ W,
    const float* __restrict__ bias, u16* __restrict__ out)
{
    __shared__ float hs[FOUT * 3 * FIN];
    __shared__ float bs[FOUT];
    for (int i = threadIdx.x; i < FOUT * 3 * FIN; i += 256) hs[i] = W[i];
    if (threadIdx.x < FOUT) bs[threadIdx.x] = bias[threadIdx.x];
    __syncthreads();

    const int nb = NN / 256;                 // 16
    const int b  = blockIdx.x / nb;
    const int n  = (blockIdx.x % nb) * 256 + threadIdx.x;

    float zv[3][FIN];
    const u16* zp0 = z0 + (size_t)b * FIN * NN + n;
    const u16* zp1 = z1 + (size_t)b * FIN * NN + n;
    const u16* zp2 = z2 + (size_t)b * FIN * NN + n;
#pragma unroll
    for (int f = 0; f < FIN; ++f) {
        zv[0][f] = bf2f(zp0[(size_t)f * NN]);
        zv[1][f] = bf2f(zp1[(size_t)f * NN]);
        zv[2][f] = bf2f(zp2[(size_t)f * NN]);
    }

    u16* op = out + (size_t)b * FOUT * NN + n;
    for (int g = 0; g < FOUT; ++g) {
        float acc = bs[g];
#pragma unroll
        for (int k = 0; k < 3; ++k)
#pragma unroll
            for (int f = 0; f < FIN; ++f)
                acc = fmaf(hs[(g * 3 + k) * FIN + f], zv[k][f], acc);
        op[(size_t)g * NN] = f2bf(fmaxf(acc, 0.f));
    }
}

// ---------------------------------------------------------------------------
// MLP layer 1, split-K: h1raw[b,j] += sum_{slice} y[b,i]*Wm1[j,i].
// y is bf16; Wm1 f32. grid: (64, 8); h1raw pre-zeroed; bias+ReLU in mlp2.
// ---------------------------------------------------------------------------
__global__ __launch_bounds__(256) void mlp1(const u16* __restrict__ y,
                                            const float* __restrict__ Wm1,
                                            float* __restrict__ h1raw)
{
    const int j    = blockIdx.x;
    const int base = blockIdx.y * 8192;
    const int D    = 16 * NN;  // 65536

    float acc[BB];
#pragma unroll
    for (int b = 0; b < BB; ++b) acc[b] = 0.f;

    const float* wrow = Wm1 + (size_t)j * D + base;
    for (int idx = threadIdx.x * 8; idx < 8192; idx += 256 * 8) {
        float4 w0 = *(const float4*)(wrow + idx);
        float4 w1 = *(const float4*)(wrow + idx + 4);
#pragma unroll
        for (int b = 0; b < BB; ++b) {
            uint4 yv = *(const uint4*)(y + (size_t)b * D + base + idx);
            union { u32 i; float f; } c[8];
            c[0].i = yv.x << 16; c[1].i = yv.x & 0xFFFF0000u;
            c[2].i = yv.y << 16; c[3].i = yv.y & 0xFFFF0000u;
            c[4].i = yv.z << 16; c[5].i = yv.z & 0xFFFF0000u;
            c[6].i = yv.w << 16; c[7].i = yv.w & 0xFFFF0000u;
            acc[b] = fmaf(w0.x, c[0].f, acc[b]);
            acc[b] = fmaf(w0.y, c[1].f, acc[b]);
            acc[b] = fmaf(w0.z, c[2].f, acc[b]);
            acc[b] = fmaf(w0.w, c[3].f, acc[b]);
            acc[b] = fmaf(w1.x, c[4].f, acc[b]);
            acc[b] = fmaf(w1.y, c[5].f, acc[b]);
            acc[b] = fmaf(w1.z, c[6].f, acc[b]);
            acc[b] = fmaf(w1.w, c[7].f, acc[b]);
        }
    }

    __shared__ float red[BB][4];
    const int lane = threadIdx.x & 63;
    const int w    = threadIdx.x >> 6;
#pragma unroll
    for (int b = 0; b < BB; ++b) {
        float v = acc[b];
        for (int off = 32; off > 0; off >>= 1) v += __shfl_down(v, off, 64);
        if (lane == 0) red[b][w] = v;
    }
    __syncthreads();
    if (threadIdx.x < BB) {
        const int b = threadIdx.x;
        atomicAdd(&h1raw[b * 64 + j],
                  red[b][0] + red[b][1] + red[b][2] + red[b][3]);
    }
}

// ---------------------------------------------------------------------------
// MLP layer 2 (+ layer-1 bias/ReLU). 1 block, 64 lanes.
// ---------------------------------------------------------------------------
__global__ void mlp2(const float* __restrict__ h1raw,
                     const float* __restrict__ bm1,
                     const float* __restrict__ Wm2,
                     const float* __restrict__ bm2, float* __restrict__ out)
{
    const int lane = threadIdx.x;  // 0..63
    const float w    = Wm2[lane];
    const float b1   = bm1[lane];
    const float bias = bm2[0];
    for (int b = 0; b < BB; ++b) {
        float v = fmaxf(h1raw[b * 64 + lane] + b1, 0.f) * w;
        for (int off = 32; off > 0; off >>= 1) v += __shfl_down(v, off, 64);
        if (lane == 0) out[b] = v + bias;
    }
}

// ---------------------------------------------------------------------------
extern "C" void kernel_launch(void* const* d_in, const int* in_sizes, int n_in,
                              void* d_out, int out_size, void* d_ws, size_t ws_size,
                              hipStream_t stream)
{
    const float* x   = (const float*)d_in[0];   // [8,16,4096]
    const float* Sc  = (const float*)d_in[1];   // [1,4096,4096]
    const float* Sl  = (const float*)d_in[2];   // [1,4096,4096]
    const float* Wc1 = (const float*)d_in[3];
    const float* bc1 = (const float*)d_in[4];
    const float* Wc2 = (const float*)d_in[5];
    const float* bc2 = (const float*)d_in[6];
    const float* Wl1 = (const float*)d_in[7];
    const float* bl1 = (const float*)d_in[8];
    const float* Wl2 = (const float*)d_in[9];
    const float* bl2 = (const float*)d_in[10];
    const float* Wm1 = (const float*)d_in[11];  // [64,65536]
    const float* bm1 = (const float*)d_in[12];
    const float* Wm2 = (const float*)d_in[13];  // [1,64]
    const float* bm2 = (const float*)d_in[14];
    float* out = (float*)d_out;                 // [8,1] f32

    char* ws = (char*)d_ws;                      // proven >= 81.02 MB
    u16*   part = (u16*)(ws);                    // 8 MB partial planes
    u16*   zb1  = (u16*)(ws + (8u  << 20));      // 2 MB
    u16*   zb2  = (u16*)(ws + (10u << 20));      // 2 MB
    u16*   yPa  = (u16*)(ws + (12u << 20));      // 2 MB
    u16*   yPb  = (u16*)(ws + (14u << 20));      // 2 MB
    float* h1   = (float*)(ws + (16u << 20));    // 2 KB
    u16*   Scb  = (u16*)(ws + (17u << 20));      // 32 MB
    u16*   Slb  = Scb + (size_t)NN * NN;         // 32 MB  (total 81.02 MB)

    const dim3 blk(256);
    const dim3 gridCmb(BB * NN / 256);           // 128
    const dim3 g2(64, 1, 8);                     // M=128: 512 blocks, 8 iters
    const dim3 g4(64, 2, 4);                     // M=256: 512 blocks, 16 iters
    const int  pl128 = 128 * NN;                 // plane elems, M=128
    const int  pl256 = 256 * NN;                 // plane elems, M=256

    cvt_f32_bf16<<<1024, blk, 0, stream>>>(Sc, Scb, NN * NN);
    cvt_f32_bf16<<<1024, blk, 0, stream>>>(Sl, Slb, NN * NN);
    cvt_f32_bf16<<<512, blk, 0, stream>>>(x, yPa, 128 * NN);

    // Layer 1: clique, Fin=16 (M=128) -> Fout=32
    diffuse<<<g2, blk, 0, stream>>>(yPa, Scb, part);
    reduce_part<8><<<256, blk, 0, stream>>>(part, pl128, zb1);
    diffuse<<<g2, blk, 0, stream>>>(zb1, Scb, part);
    reduce_part<8><<<256, blk, 0, stream>>>(part, pl128, zb2);
    combine_relu<16, 32><<<gridCmb, blk, 0, stream>>>(yPa, zb1, zb2, Wc1, bc1, yPb);
    // Layer 2: clique, Fin=32 (M=256) -> Fout=16
    diffuse<<<g4, blk, 0, stream>>>(yPb, Scb, part);
    reduce_part<4><<<512, blk, 0, stream>>>(part, pl256, zb1);
    diffuse<<<g4, blk, 0, stream>>>(zb1, Scb, part);
    reduce_part<4><<<512, blk, 0, stream>>>(part, pl256, zb2);
    combine_relu<32, 16><<<gridCmb, blk, 0, stream>>>(yPb, zb1, zb2, Wc2, bc2, yPa);
    // Layer 3: line, Fin=16 (M=128) -> Fout=32
    diffuse<<<g2, blk, 0, stream>>>(yPa, Slb, part);
    reduce_part<8><<<256, blk, 0, stream>>>(part, pl128, zb1);
    diffuse<<<g2, blk, 0, stream>>>(zb1, Slb, part);
    reduce_part<8><<<256, blk, 0, stream>>>(part, pl128, zb2);
    combine_relu<16, 32><<<gridCmb, blk, 0, stream>>>(yPa, zb1, zb2, Wl1, bl1, yPb);
    // Layer 4: line, Fin=32 (M=256) -> Fout=16
    diffuse<<<g4, blk, 0, stream>>>(yPb, Slb, part);
    reduce_part<4><<<512, blk, 0, stream>>>(part, pl256, zb1);
    diffuse<<<g4, blk, 0, stream>>>(zb1, Slb, part);
    reduce_part<4><<<512, blk, 0, stream>>>(part, pl256, zb2);
    combine_relu<32, 16><<<gridCmb, blk, 0, stream>>>(yPb, zb1, zb2, Wl2, bl2, yPa);
    // MLP
    hipMemsetAsync(h1, 0, 64 * BB * sizeof(float), stream);
    mlp1<<<dim3(64, 8), blk, 0, stream>>>(yPa, Wm1, h1);
    mlp2<<<1, 64, 0, stream>>>(h1, bm1, Wm2, bm2, out);
}